// Round 9
// baseline (125.754 us; speedup 1.0000x reference)
//
#include <hip/hip_runtime.h>
#include <stdint.h>

#define N_ROWS 65536
#define K_CODES 1024
#define D 64
#define OUT_ELEMS 4194304
#define LOSS_SCALE (1.25f / 4194304.0f)
#define ROWS_PER_BLOCK 128
#define GRID_DIST (N_ROWS / ROWS_PER_BLOCK)  // 512 blocks = 2/CU
#define SETS (ROWS_PER_BLOCK / 16)           // 8 sets of 16 rows

typedef short short8 __attribute__((ext_vector_type(8)));
typedef float f32x4 __attribute__((ext_vector_type(4)));

__device__ __forceinline__ unsigned short f2bf(float f) {
    unsigned int u = __float_as_uint(f);
    return (unsigned short)((u + 0x7fffu + ((u >> 16) & 1u)) >> 16);  // RNE
}
__device__ __forceinline__ short8 pack8(float4 a, float4 b) {
    short8 r;
    r[0] = f2bf(a.x); r[1] = f2bf(a.y); r[2] = f2bf(a.z); r[3] = f2bf(a.w);
    r[4] = f2bf(b.x); r[5] = f2bf(b.y); r[6] = f2bf(b.z); r[7] = f2bf(b.w);
    return r;
}

// Code-stationary VQ, lean-loop edition.
// 512-thread blocks, grid 512 (2 blocks/CU = 4 waves/SIMD). Wave owns 128
// codes as 8 B-frag VGPR tiles (64 regs, no spill). K-loop per 16-row set:
// z load+pack, 16 MFMA, float-domain packed keys (trunc dist | 10-bit code,
// v_min_f32 reduction — monotone for both signs; ties ~numpy-first for
// positive dists, within-truncation flips otherwise, all inside the
// structural 2/1024 absmax already measured). NO z2, NO barriers, NO global
// gathers in the loop. Keys for all 8 sets accumulate in 4KB LDS; ONE
// __syncthreads; final phase does cross-wave min + coalesced quantize-write
// + exact fp32 loss (z re-read is L2-hot).
__global__ __launch_bounds__(512, 4) void vq_kernel(
        const float* __restrict__ z, const float* __restrict__ emb,
        float* __restrict__ out, float* __restrict__ partials) {
    const int tid = threadIdx.x;
    const int w = tid >> 6, lane = tid & 63;
    const int n = lane & 15, q = lane >> 4;
    __shared__ float sh_key[SETS][8][16];  // [set][wave][rowInSet]
    __shared__ float ps[8];
    const int r0 = blockIdx.x * ROWS_PER_BLOCK;

    // --- Stationary codebook: wave w owns codes [w*128, w*128+128) as 8 tiles.
    // B-frag: code = lane&15, dims q*8..+8 (+32 for K-half 1); pre-scaled by -2
    // so MFMA acc = e2 - 2 z.e directly. e2 exact fp32 over all 64 dims.
    const int cbase = w * 128 + n;
    short8 cb0[8], cb1[8];
    float e2w[8];
#pragma unroll
    for (int ct = 0; ct < 8; ct++) {
        const float* er = emb + (size_t)(cbase + ct * 16) * D + q * 8;
        float4 g0 = *(const float4*)(er);      float4 g1 = *(const float4*)(er + 4);
        float4 g2 = *(const float4*)(er + 32); float4 g3 = *(const float4*)(er + 36);
        float e2p = g0.x*g0.x + g0.y*g0.y + g0.z*g0.z + g0.w*g0.w
                  + g1.x*g1.x + g1.y*g1.y + g1.z*g1.z + g1.w*g1.w
                  + g2.x*g2.x + g2.y*g2.y + g2.z*g2.z + g2.w*g2.w
                  + g3.x*g3.x + g3.y*g3.y + g3.z*g3.z + g3.w*g3.w;
        e2p += __shfl_xor(e2p, 16, 64);
        e2p += __shfl_xor(e2p, 32, 64);
        e2w[ct] = e2p;
        float4 m0 = {-2.f*g0.x, -2.f*g0.y, -2.f*g0.z, -2.f*g0.w};
        float4 m1 = {-2.f*g1.x, -2.f*g1.y, -2.f*g1.z, -2.f*g1.w};
        float4 m2 = {-2.f*g2.x, -2.f*g2.y, -2.f*g2.z, -2.f*g2.w};
        float4 m3 = {-2.f*g3.x, -2.f*g3.y, -2.f*g3.z, -2.f*g3.w};
        cb0[ct] = pack8(m0, m1);
        cb1[ct] = pack8(m2, m3);
    }

    // --- K-loop: 8 sets, zero barriers, waves fully decoupled.
    for (int s = 0; s < SETS; s++) {
        const float* zr = z + (size_t)(r0 + s * 16 + n) * D + q * 8;
        float4 c0 = *(const float4*)(zr);      float4 c1 = *(const float4*)(zr + 4);
        float4 c2 = *(const float4*)(zr + 32); float4 c3 = *(const float4*)(zr + 36);
        short8 alo = pack8(c0, c1), ahi = pack8(c2, c3);  // A: row=lane&15, k=q*8+j

        float best[4] = {__builtin_huge_valf(), __builtin_huge_valf(),
                         __builtin_huge_valf(), __builtin_huge_valf()};
#pragma unroll
        for (int ct = 0; ct < 8; ct++) {
            f32x4 acc = {e2w[ct], e2w[ct], e2w[ct], e2w[ct]};
            acc = __builtin_amdgcn_mfma_f32_16x16x32_bf16(alo, cb0[ct], acc, 0, 0, 0);
            acc = __builtin_amdgcn_mfma_f32_16x16x32_bf16(ahi, cb1[ct], acc, 0, 0, 0);
            const unsigned int id = (unsigned int)(cbase + ct * 16);
#pragma unroll
            for (int r = 0; r < 4; r++) {
                float kf = __uint_as_float((__float_as_uint(acc[r]) & 0xFFFFFC00u) | id);
                best[r] = __builtin_fminf(best[r], kf);
            }
        }
        // min over the wave's 16 code-columns (4 indep 4-step chains)
#pragma unroll
        for (int r = 0; r < 4; r++)
#pragma unroll
            for (int x = 1; x < 16; x <<= 1)
                best[r] = __builtin_fminf(best[r], __shfl_xor(best[r], x, 64));
        if (n == 0)  // quad q holds rows q*4..q*4+3
            *(float4*)&sh_key[s][w][q << 2] =
                make_float4(best[0], best[1], best[2], best[3]);
    }
    __syncthreads();  // the ONLY barrier

    // --- Final: cross-wave min, coalesced quantize-write, exact fp32 loss.
    float lossacc = 0.f;
    const float4* emb4 = (const float4*)emb;
    const float4* z4 = (const float4*)z + (size_t)r0 * 16;
    float4* o4 = (float4*)out + (size_t)r0 * 16;
#pragma unroll
    for (int it = 0; it < 4; it++) {
        int u = it * 512 + tid;            // [0, 2048) float4 units of this block
        int row = u >> 4, unit = u & 15;
        int s = row >> 4, ri = row & 15;
        float km = sh_key[s][0][ri];
#pragma unroll
        for (int ww = 1; ww < 8; ww++)
            km = __builtin_fminf(km, sh_key[s][ww][ri]);  // broadcast reads
        int idx = (int)(__float_as_uint(km) & 1023u);
        float4 qv = emb4[idx * 16 + unit];  // L2-hot codebook gather
        float4 zv = z4[u];                  // L2-hot re-read
        o4[u] = qv;
        float dx = qv.x - zv.x, dy = qv.y - zv.y, dz = qv.z - zv.z, dw = qv.w - zv.w;
        lossacc += dx * dx + dy * dy + dz * dz + dw * dw;
    }
#pragma unroll
    for (int off = 32; off > 0; off >>= 1)
        lossacc += __shfl_down(lossacc, off, 64);
    if (lane == 0) ps[w] = lossacc;
    __syncthreads();
    if (tid == 0) {
        float s8 = 0.f;
#pragma unroll
        for (int ww = 0; ww < 8; ww++) s8 += ps[ww];
        partials[blockIdx.x] = s8;
    }
}

// Single block: sum 512 partials -> loss (no atomics anywhere).
__global__ __launch_bounds__(256) void loss_kernel(const float* __restrict__ partials,
                                                   float* __restrict__ loss) {
    float s = partials[threadIdx.x] + partials[threadIdx.x + 256];
#pragma unroll
    for (int off = 32; off > 0; off >>= 1)
        s += __shfl_down(s, off, 64);
    __shared__ float ps[4];
    int wave = threadIdx.x >> 6, lane = threadIdx.x & 63;
    if (lane == 0) ps[wave] = s;
    __syncthreads();
    if (threadIdx.x == 0) loss[0] = (ps[0] + ps[1] + ps[2] + ps[3]) * LOSS_SCALE;
}

extern "C" void kernel_launch(void* const* d_in, const int* in_sizes, int n_in,
                              void* d_out, int out_size, void* d_ws, size_t ws_size,
                              hipStream_t stream) {
    const float* z = (const float*)d_in[0];
    const float* emb = (const float*)d_in[1];
    float* out = (float*)d_out;
    float* loss = out + OUT_ELEMS;
    float* partials = (float*)d_ws;  // 2 KiB

    vq_kernel<<<GRID_DIST, 512, 0, stream>>>(z, emb, out, partials);
    loss_kernel<<<1, 256, 0, stream>>>(partials, loss);
}